// Round 1
// baseline (20715.471 us; speedup 1.0000x reference)
//
#include <hip/hip_runtime.h>
#include <hip/hip_bf16.h>
#include <stdint.h>

// ---------------------------------------------------------------------------
// QLSTM  (T=512, B=64, D=1024, H=1024)
//   Phase 1: Gx = x @ Wx + b      -- parallel bf16 MFMA GEMM [32768x1024]@[1024x4096]
//   Phase 2: persistent kernel, 512 steps:
//              gates = Gx[t] + h @ Wh   (Wh fragments pinned in registers)
//              c = f*c + i*g ; h = o*tanh(c)   (fp32 state in registers)
//            one device-scope grid barrier per step, h double-buffered.
// ---------------------------------------------------------------------------

typedef unsigned short u16;
typedef __attribute__((ext_vector_type(8))) short s16x8;   // bf16x8 MFMA frag (4 VGPRs)
typedef __attribute__((ext_vector_type(4))) float f32x4;   // MFMA accumulator

static constexpr int T_ = 512, B_ = 64, D_ = 1024, H_ = 1024;
static constexpr int MX_ = T_ * B_;      // 32768 rows of x_flat
static constexpr int NG_ = 4 * H_;       // 4096 gate cols

__device__ __forceinline__ u16 f2bf(float f) {
  union { __hip_bfloat16 b; u16 u; } v;
  v.b = __float2bfloat16(f);
  return v.u;
}
__device__ __forceinline__ float bf2f(u16 u) {
  union { __hip_bfloat16 b; u16 u; } v;
  v.u = u;
  return __bfloat162float(v.b);
}

__device__ __forceinline__ void gload_lds16(const u16* g, u16* l) {
  // async global->LDS, 16B per lane; LDS dest is wave-uniform base + lane*16
  __builtin_amdgcn_global_load_lds(
      (const __attribute__((address_space(1))) unsigned int*)(g),
      (__attribute__((address_space(3))) unsigned int*)(l), 16, 0, 0);
}

__device__ __forceinline__ float sigm(float x) {
  return __builtin_amdgcn_rcpf(1.f + __expf(-x));
}
__device__ __forceinline__ float tanh_(float x) {
  return 2.f * __builtin_amdgcn_rcpf(1.f + __expf(-2.f * x)) - 1.f;
}

__device__ __forceinline__ float gxload(const float* p) { return *p; }
__device__ __forceinline__ float gxload(const u16* p) { return bf2f(*p); }
__device__ __forceinline__ void gxstore(float* p, float v) { *p = v; }
__device__ __forceinline__ void gxstore(u16* p, float v) { *p = f2bf(v); }

// ---------------------------------------------------------------------------
// x (fp32) -> bf16, 8 elems/thread
__global__ __launch_bounds__(256) void k_cast_x(const float* __restrict__ x,
                                                u16* __restrict__ xb) {
  size_t i = ((size_t)blockIdx.x * 256 + threadIdx.x) * 8;
  const float4* xp = (const float4*)(x + i);
  float4 a = xp[0], b = xp[1];
  s16x8 o;
  o[0] = (short)f2bf(a.x); o[1] = (short)f2bf(a.y);
  o[2] = (short)f2bf(a.z); o[3] = (short)f2bf(a.w);
  o[4] = (short)f2bf(b.x); o[5] = (short)f2bf(b.y);
  o[6] = (short)f2bf(b.z); o[7] = (short)f2bf(b.w);
  *(s16x8*)(xb + i) = o;
}

// ---------------------------------------------------------------------------
// Weight prep:
//  wxt [4096 n][1024 k] bf16 :  wxt[n][k] = W_{n>>10}[k][n&1023]        (B^T for GEMM)
//  whr [64 g][64 c][1024 k] bf16 : interleaved (hcol,gate) column order for recurrent
//      c: gate = c&3, hcol_local = (c>>4)*4 + ((c>>2)&3)
//  biasf [4096] fp32 fused bias
__global__ __launch_bounds__(256) void k_prep_w(
    const float* __restrict__ Wf, const float* __restrict__ Wi,
    const float* __restrict__ Wg, const float* __restrict__ Wo,
    const float* __restrict__ bf_, const float* __restrict__ bi_,
    const float* __restrict__ bg_, const float* __restrict__ bo_,
    u16* __restrict__ wxt, u16* __restrict__ whr, float* __restrict__ biasf) {
  const int bid = blockIdx.x;            // 0..4095
  const int t = threadIdx.x;
  const float* Ws[4] = {Wf, Wi, Wg, Wo};
  {
    const float* src = Ws[bid >> 10];
    const int col = bid & 1023;
#pragma unroll
    for (int it = 0; it < 4; ++it) {
      int k = t + it * 256;
      wxt[(size_t)bid * 1024 + k] = f2bf(src[(size_t)k * 1024 + col]);
    }
  }
  {
    const int g = bid >> 6, c = bid & 63;
    const float* src = Ws[c & 3];
    const int col = g * 16 + ((c >> 4) << 2) + ((c >> 2) & 3);
#pragma unroll
    for (int it = 0; it < 4; ++it) {
      int k = t + it * 256;
      whr[(size_t)bid * 1024 + k] = f2bf(src[(size_t)(1024 + k) * 1024 + col]);
    }
  }
  if (t == 0) {
    const float* bs[4] = {bf_, bi_, bg_, bo_};
    biasf[bid] = bs[bid >> 10][bid & 1023];
  }
}

// ---------------------------------------------------------------------------
// Gx = x_bf16 @ WxT^T + bias.  m97-style 128x128 tile, BK=32, 256 threads.
template <typename GT>
__global__ __launch_bounds__(256) void k_gemm_gx(
    const u16* __restrict__ A,    // [32768][1024]
    const u16* __restrict__ Bt,   // [4096][1024]  (row = n)
    const float* __restrict__ biasf,
    GT* __restrict__ C) {         // [32768][4096]
  __shared__ u16 aLds[128 * 32];
  __shared__ u16 bLds[128 * 32];
  const int tid = threadIdx.x;
  const int w = tid >> 6, l = tid & 63;
  const int q = l >> 4, cc = l & 15;
  const int bm = blockIdx.x, bn = blockIdx.y;
  const int wm = (w & 1) * 64, wn = (w >> 1) * 64;
  const int lrow = l >> 2, lchunk = (l & 3) * 8;

  f32x4 zero = {0.f, 0.f, 0.f, 0.f};
  f32x4 acc[4][4];
#pragma unroll
  for (int i = 0; i < 4; ++i)
#pragma unroll
    for (int j = 0; j < 4; ++j) acc[i][j] = zero;

  for (int k0 = 0; k0 < 1024; k0 += 32) {
#pragma unroll
    for (int r = 0; r < 2; ++r) {
      gload_lds16(A + (size_t)(bm * 128 + r * 64 + w * 16 + lrow) * 1024 + k0 + lchunk,
                  &aLds[(r * 64 + w * 16) * 32]);
      gload_lds16(Bt + (size_t)(bn * 128 + r * 64 + w * 16 + lrow) * 1024 + k0 + lchunk,
                  &bLds[(r * 64 + w * 16) * 32]);
    }
    __syncthreads();
    s16x8 af[4], bf[4];
#pragma unroll
    for (int i = 0; i < 4; ++i)
      af[i] = *(const s16x8*)&aLds[(wm + i * 16 + cc) * 32 + q * 8];
#pragma unroll
    for (int j = 0; j < 4; ++j)
      bf[j] = *(const s16x8*)&bLds[(wn + j * 16 + cc) * 32 + q * 8];
#pragma unroll
    for (int i = 0; i < 4; ++i)
#pragma unroll
      for (int j = 0; j < 4; ++j)
        acc[i][j] = __builtin_amdgcn_mfma_f32_16x16x32_bf16(af[i], bf[j], acc[i][j], 0, 0, 0);
    __syncthreads();
  }
#pragma unroll
  for (int i = 0; i < 4; ++i) {
    const int row0 = bm * 128 + wm + i * 16 + q * 4;
#pragma unroll
    for (int j = 0; j < 4; ++j) {
      const int col = bn * 128 + wn + j * 16 + cc;
      const float bb = biasf[col];
#pragma unroll
      for (int r = 0; r < 4; ++r)
        gxstore(C + (size_t)(row0 + r) * 4096 + col, acc[i][j][r] + bb);
    }
  }
}

// ---------------------------------------------------------------------------
// Persistent recurrent kernel. 256 blocks x 256 threads (4 waves), no LDS.
// block: m = bid>>6 (batch tile of 16), g = bid&63 (16 h-cols -> 64 gate cols).
// wave w owns 16 tile cols cc: gate = cc&3, hcol = g*16 + w*4 + (cc>>2).
template <typename GT>
__global__ __launch_bounds__(256, 1) void k_lstm(
    const u16* __restrict__ Whr,   // [64][64][1024]
    const GT* __restrict__ Gx,     // [32768][4096]
    u16* __restrict__ hbuf,        // [2][64][1024] bf16 (buf 0 zeroed)
    float* __restrict__ out,       // stacked [512][64][1024], hT[64][1024], cT[64][1024]
    unsigned* __restrict__ bar) {  // zeroed monotonic barrier counter
  const int tid = threadIdx.x;
  const int w = tid >> 6, l = tid & 63, q = l >> 4, cc = l & 15;
  const int m = blockIdx.x >> 6, g = blockIdx.x & 63;
  const int gate = cc & 3;
  const int hcol = g * 16 + w * 4 + (cc >> 2);
  const int gxcol = gate * 1024 + hcol;
  const int nb = (int)gridDim.x;

  // Pin Wh B-fragments in registers: 32 K-steps x 8 bf16 = 128 VGPRs/lane.
  s16x8 bfr[32];
  {
    const u16* wp = Whr + (size_t)(g * 64 + w * 16 + cc) * 1024 + q * 8;
#pragma unroll
    for (int kk = 0; kk < 32; ++kk) bfr[kk] = *(const s16x8*)(wp + kk * 32);
  }
  const int arow = m * 16 + cc;   // A-frag row (batch index) for this lane
  float cst[4] = {0.f, 0.f, 0.f, 0.f};
  float hlast[4] = {0.f, 0.f, 0.f, 0.f};

  for (int t = 0; t < T_; ++t) {
    const u16* hs = hbuf + (size_t)(t & 1) * (B_ * H_) + (size_t)arow * 1024 + q * 8;
    const GT* gp = Gx + (size_t)(t * 64 + m * 16 + q * 4) * 4096 + gxcol;
    float gxv[4];
#pragma unroll
    for (int r = 0; r < 4; ++r) gxv[r] = gxload(gp + (size_t)r * 4096);

    f32x4 acc = {0.f, 0.f, 0.f, 0.f};
#pragma unroll
    for (int kk = 0; kk < 32; ++kk) {
      s16x8 a = *(const s16x8*)(hs + kk * 32);
      acc = __builtin_amdgcn_mfma_f32_16x16x32_bf16(a, bfr[kk], acc, 0, 0, 0);
    }

    float v0[4];
#pragma unroll
    for (int r = 0; r < 4; ++r) {
      float x = acc[r] + gxv[r];
      v0[r] = (gate == 2) ? tanh_(x) : sigm(x);
    }
#pragma unroll
    for (int r = 0; r < 4; ++r) {
      float a0 = v0[r];
      float a1 = __shfl_xor(a0, 1);
      float a2 = __shfl_xor(a0, 2);
      float a3 = __shfl_xor(a1, 2);           // value from lane^3
      // aX holds gate (my_gate ^ X); select f,i,g,o
      float fv = (gate == 0) ? a0 : (gate == 1) ? a1 : (gate == 2) ? a2 : a3;
      float iv = (gate == 0) ? a1 : (gate == 1) ? a0 : (gate == 2) ? a3 : a2;
      float gv = (gate == 0) ? a2 : (gate == 1) ? a3 : (gate == 2) ? a0 : a1;
      float ov = (gate == 0) ? a3 : (gate == 1) ? a2 : (gate == 2) ? a1 : a0;
      float cn = fv * cst[r] + iv * gv;
      cst[r] = cn;
      hlast[r] = ov * tanh_(cn);
    }
    if (gate == 0) {
      u16* hd = hbuf + (size_t)((t + 1) & 1) * (B_ * H_);
#pragma unroll
      for (int r = 0; r < 4; ++r) {
        const int row = m * 16 + q * 4 + r;
        out[(size_t)(t * 64 + row) * 1024 + hcol] = hlast[r];
        hd[row * 1024 + hcol] = f2bf(hlast[r]);
      }
    }
    // -------- grid barrier (monotonic counter, device scope) --------
    __syncthreads();   // drains each wave's stores (vmcnt 0) before arrive
    if (tid == 0)
      __hip_atomic_fetch_add(bar, 1u, __ATOMIC_RELEASE, __HIP_MEMORY_SCOPE_AGENT);
    if (l == 0) {
      const unsigned target = (unsigned)(nb * (t + 1));
      while (__hip_atomic_load(bar, __ATOMIC_RELAXED, __HIP_MEMORY_SCOPE_AGENT) < target)
        __builtin_amdgcn_s_sleep(1);
      (void)__hip_atomic_load(bar, __ATOMIC_ACQUIRE, __HIP_MEMORY_SCOPE_AGENT);
    }
    __syncthreads();
  }
  if (gate == 0) {
    float* hT = out + (size_t)T_ * B_ * H_;
    float* cT = hT + B_ * H_;
#pragma unroll
    for (int r = 0; r < 4; ++r) {
      const int row = m * 16 + q * 4 + r;
      hT[row * 1024 + hcol] = hlast[r];
      cT[row * 1024 + hcol] = cst[r];
    }
  }
}

// ---------------------------------------------------------------------------
extern "C" void kernel_launch(void* const* d_in, const int* in_sizes, int n_in,
                              void* d_out, int out_size, void* d_ws, size_t ws_size,
                              hipStream_t stream) {
  (void)in_sizes; (void)n_in; (void)out_size;
  const float* x   = (const float*)d_in[0];
  const float* Wf  = (const float*)d_in[1];
  const float* bf_ = (const float*)d_in[2];
  const float* Wi  = (const float*)d_in[3];
  const float* bi_ = (const float*)d_in[4];
  const float* Wg  = (const float*)d_in[5];
  const float* bg_ = (const float*)d_in[6];
  const float* Wo  = (const float*)d_in[7];
  const float* bo_ = (const float*)d_in[8];
  float* out = (float*)d_out;

  uint8_t* ws = (uint8_t*)d_ws;
  const size_t n_gx    = (size_t)MX_ * NG_;
  const size_t sz_xb   = (size_t)MX_ * 1024 * 2;   // 64 MB
  const size_t sz_wxt  = (size_t)4096 * 1024 * 2;  // 8 MB
  const size_t sz_whr  = (size_t)4096 * 1024 * 2;  // 8 MB
  const size_t sz_bias = 4096 * 4;
  const size_t sz_hbuf = (size_t)2 * 64 * 1024 * 2;
  const size_t sz_ctrl = 256;
  const size_t fixed = sz_xb + sz_wxt + sz_whr + sz_bias + sz_hbuf + sz_ctrl + 1024;
  const bool f32gx = ws_size >= fixed + n_gx * 4;  // fp32 Gx (512 MB) if it fits
  const size_t sz_gx = n_gx * (f32gx ? 4 : 2);

  size_t off = 0;
  uint8_t* p_gx   = ws;                  off += sz_gx;
  u16*     xb     = (u16*)(ws + off);    off += sz_xb;
  u16*     wxt    = (u16*)(ws + off);    off += sz_wxt;
  u16*     whr    = (u16*)(ws + off);    off += sz_whr;
  float*   biasf  = (float*)(ws + off);  off += sz_bias;
  u16*     hbuf   = (u16*)(ws + off);    off += sz_hbuf;
  unsigned* bar   = (unsigned*)(ws + off);

  // zero h0 (both h buffers) + barrier counter (contiguous)
  hipMemsetAsync(hbuf, 0, sz_hbuf + sz_ctrl, stream);
  k_cast_x<<<(MX_ * 1024) / (256 * 8), 256, 0, stream>>>(x, xb);
  k_prep_w<<<4096, 256, 0, stream>>>(Wf, Wi, Wg, Wo, bf_, bi_, bg_, bo_, wxt, whr, biasf);
  if (f32gx) {
    k_gemm_gx<float><<<dim3(256, 32), 256, 0, stream>>>(xb, wxt, biasf, (float*)p_gx);
    k_lstm<float><<<256, 256, 0, stream>>>(whr, (const float*)p_gx, hbuf, out, bar);
  } else {
    k_gemm_gx<u16><<<dim3(256, 32), 256, 0, stream>>>(xb, wxt, biasf, (u16*)p_gx);
    k_lstm<u16><<<256, 256, 0, stream>>>(whr, (const u16*)p_gx, hbuf, out, bar);
  }
}

// Round 2
// 7456.345 us; speedup vs baseline: 2.7782x; 2.7782x over previous
//
#include <hip/hip_runtime.h>
#include <hip/hip_bf16.h>
#include <stdint.h>

// ---------------------------------------------------------------------------
// QLSTM  (T=512, B=64, D=1024, H=1024)
//   Phase 1: Gx = x @ Wx + b      -- parallel bf16 MFMA GEMM [32768x1024]@[1024x4096]
//   Phase 2: persistent kernel, 512 steps:
//              gates = Gx[t] + h @ Wh   (Wh resident in LDS, 128KB/block)
//              c = f*c + i*g ; h = o*tanh(c)   (fp32 state in registers)
//            4 independent per-m-group flag-vector barriers (no atomic RMW),
//            h double-buffered in global, Gx prefetched across the barrier.
// ---------------------------------------------------------------------------

typedef unsigned short u16;
typedef __attribute__((ext_vector_type(8))) short s16x8;   // bf16x8 MFMA frag (4 VGPRs)
typedef __attribute__((ext_vector_type(4))) float f32x4;   // MFMA accumulator

static constexpr int T_ = 512, B_ = 64, D_ = 1024, H_ = 1024;
static constexpr int MX_ = T_ * B_;      // 32768 rows of x_flat
static constexpr int NG_ = 4 * H_;       // 4096 gate cols

__device__ __forceinline__ u16 f2bf(float f) {
  union { __hip_bfloat16 b; u16 u; } v;
  v.b = __float2bfloat16(f);
  return v.u;
}
__device__ __forceinline__ float bf2f(u16 u) {
  union { __hip_bfloat16 b; u16 u; } v;
  v.u = u;
  return __bfloat162float(v.b);
}

__device__ __forceinline__ void gload_lds16(const u16* g, u16* l) {
  __builtin_amdgcn_global_load_lds(
      (const __attribute__((address_space(1))) unsigned int*)(g),
      (__attribute__((address_space(3))) unsigned int*)(l), 16, 0, 0);
}

__device__ __forceinline__ float sigm(float x) {
  return __builtin_amdgcn_rcpf(1.f + __expf(-x));
}
__device__ __forceinline__ float tanh_(float x) {
  return 2.f * __builtin_amdgcn_rcpf(1.f + __expf(-2.f * x)) - 1.f;
}

__device__ __forceinline__ float gxload(const float* p) { return *p; }
__device__ __forceinline__ float gxload(const u16* p) { return bf2f(*p); }
__device__ __forceinline__ void gxstore(float* p, float v) { *p = v; }
__device__ __forceinline__ void gxstore(u16* p, float v) { *p = f2bf(v); }

// ---------------------------------------------------------------------------
// x (fp32) -> bf16, 8 elems/thread
__global__ __launch_bounds__(256) void k_cast_x(const float* __restrict__ x,
                                                u16* __restrict__ xb) {
  size_t i = ((size_t)blockIdx.x * 256 + threadIdx.x) * 8;
  const float4* xp = (const float4*)(x + i);
  float4 a = xp[0], b = xp[1];
  s16x8 o;
  o[0] = (short)f2bf(a.x); o[1] = (short)f2bf(a.y);
  o[2] = (short)f2bf(a.z); o[3] = (short)f2bf(a.w);
  o[4] = (short)f2bf(b.x); o[5] = (short)f2bf(b.y);
  o[6] = (short)f2bf(b.z); o[7] = (short)f2bf(b.w);
  *(s16x8*)(xb + i) = o;
}

// ---------------------------------------------------------------------------
// Weight prep (unchanged from round 1; mapping verified by passing bench):
//  wxt [4096 n][1024 k] bf16 :  wxt[n][k] = W_{n>>10}[k][n&1023]
//  whr [64 g][64 c][1024 k] bf16, c: gate=c&3, hcol_local=(c>>4)*4+((c>>2)&3)
//  biasf [4096] fp32
__global__ __launch_bounds__(256) void k_prep_w(
    const float* __restrict__ Wf, const float* __restrict__ Wi,
    const float* __restrict__ Wg, const float* __restrict__ Wo,
    const float* __restrict__ bf_, const float* __restrict__ bi_,
    const float* __restrict__ bg_, const float* __restrict__ bo_,
    u16* __restrict__ wxt, u16* __restrict__ whr, float* __restrict__ biasf) {
  const int bid = blockIdx.x;            // 0..4095
  const int t = threadIdx.x;
  const float* Ws[4] = {Wf, Wi, Wg, Wo};
  {
    const float* src = Ws[bid >> 10];
    const int col = bid & 1023;
#pragma unroll
    for (int it = 0; it < 4; ++it) {
      int k = t + it * 256;
      wxt[(size_t)bid * 1024 + k] = f2bf(src[(size_t)k * 1024 + col]);
    }
  }
  {
    const int g = bid >> 6, c = bid & 63;
    const float* src = Ws[c & 3];
    const int col = g * 16 + ((c >> 4) << 2) + ((c >> 2) & 3);
#pragma unroll
    for (int it = 0; it < 4; ++it) {
      int k = t + it * 256;
      whr[(size_t)bid * 1024 + k] = f2bf(src[(size_t)(1024 + k) * 1024 + col]);
    }
  }
  if (t == 0) {
    const float* bs[4] = {bf_, bi_, bg_, bo_};
    biasf[bid] = bs[bid >> 10][bid & 1023];
  }
}

// ---------------------------------------------------------------------------
// Gx = x_bf16 @ WxT^T + bias.  m97-style 128x128 tile, BK=32, 256 threads.
template <typename GT>
__global__ __launch_bounds__(256) void k_gemm_gx(
    const u16* __restrict__ A,    // [32768][1024]
    const u16* __restrict__ Bt,   // [4096][1024]
    const float* __restrict__ biasf,
    GT* __restrict__ C) {         // [32768][4096]
  __shared__ u16 aLds[128 * 32];
  __shared__ u16 bLds[128 * 32];
  const int tid = threadIdx.x;
  const int w = tid >> 6, l = tid & 63;
  const int q = l >> 4, cc = l & 15;
  const int bm = blockIdx.x, bn = blockIdx.y;
  const int wm = (w & 1) * 64, wn = (w >> 1) * 64;
  const int lrow = l >> 2, lchunk = (l & 3) * 8;

  f32x4 zero = {0.f, 0.f, 0.f, 0.f};
  f32x4 acc[4][4];
#pragma unroll
  for (int i = 0; i < 4; ++i)
#pragma unroll
    for (int j = 0; j < 4; ++j) acc[i][j] = zero;

  for (int k0 = 0; k0 < 1024; k0 += 32) {
#pragma unroll
    for (int r = 0; r < 2; ++r) {
      gload_lds16(A + (size_t)(bm * 128 + r * 64 + w * 16 + lrow) * 1024 + k0 + lchunk,
                  &aLds[(r * 64 + w * 16) * 32]);
      gload_lds16(Bt + (size_t)(bn * 128 + r * 64 + w * 16 + lrow) * 1024 + k0 + lchunk,
                  &bLds[(r * 64 + w * 16) * 32]);
    }
    __syncthreads();
    s16x8 af[4], bf[4];
#pragma unroll
    for (int i = 0; i < 4; ++i)
      af[i] = *(const s16x8*)&aLds[(wm + i * 16 + cc) * 32 + q * 8];
#pragma unroll
    for (int j = 0; j < 4; ++j)
      bf[j] = *(const s16x8*)&bLds[(wn + j * 16 + cc) * 32 + q * 8];
#pragma unroll
    for (int i = 0; i < 4; ++i)
#pragma unroll
      for (int j = 0; j < 4; ++j)
        acc[i][j] = __builtin_amdgcn_mfma_f32_16x16x32_bf16(af[i], bf[j], acc[i][j], 0, 0, 0);
    __syncthreads();
  }
#pragma unroll
  for (int i = 0; i < 4; ++i) {
    const int row0 = bm * 128 + wm + i * 16 + q * 4;
#pragma unroll
    for (int j = 0; j < 4; ++j) {
      const int col = bn * 128 + wn + j * 16 + cc;
      const float bb = biasf[col];
#pragma unroll
      for (int r = 0; r < 4; ++r)
        gxstore(C + (size_t)(row0 + r) * 4096 + col, acc[i][j][r] + bb);
    }
  }
}

// ---------------------------------------------------------------------------
// Persistent recurrent kernel. 256 blocks x 256 threads, 128KB LDS (Wh).
// block: m = bid>>6 (batch tile of 16), g = bid&63 (16 h-cols -> 64 gate cols).
// Dependency: block (m,g) consumes only h rows of m-tile, produced by (m,*):
// 4 independent groups of 64 blocks -> per-group flag-vector barrier.
template <typename GT>
__global__ __launch_bounds__(256, 1) void k_lstm(
    const u16* __restrict__ Whr,   // [64][64][1024]
    const GT* __restrict__ Gx,     // [32768][4096]
    u16* __restrict__ hbuf,        // [2][64][1024] bf16 (buf 0 zeroed)
    float* __restrict__ out,       // stacked [512][64][1024], hT, cT
    unsigned* __restrict__ flags) {// [4][64] zeroed; group m spaced 256B
  // Wh resident in LDS. chunk (kk,q,col) at [(kk*4+q)*64 + col]; the b128
  // read cohort (8 consecutive lanes) then covers all 32 banks exactly once.
  __shared__ s16x8 wl[32 * 4 * 64];            // 128 KB
  const int tid = threadIdx.x;
  const int w = tid >> 6, l = tid & 63, q = l >> 4, cc = l & 15;
  const int m = blockIdx.x >> 6, g = blockIdx.x & 63;
  const int gate = cc & 3;
  const int hcol = g * 16 + w * 4 + (cc >> 2);
  const int gxcol = gate * 1024 + hcol;
  const int wcol = w * 16 + cc;                // this lane's B-frag column
  unsigned* gflag = flags + m * 64;

  // ---- stage Wh into LDS once (coalesced global reads) ----
  {
    const int col = tid >> 2;                  // 0..63
    const int kb = (tid & 3) * 256;            // k base
    const u16* src = Whr + (size_t)(g * 64 + col) * 1024 + kb;
#pragma unroll
    for (int i = 0; i < 8; ++i) {
      const int kk = kb / 32 + i;
#pragma unroll
      for (int qq = 0; qq < 4; ++qq)
        wl[(kk * 4 + qq) * 64 + col] = *(const s16x8*)(src + i * 32 + qq * 8);
    }
  }
  __syncthreads();

  const int arow = m * 16 + cc;                // A-frag row (batch index)
  float cst[4] = {0.f, 0.f, 0.f, 0.f};
  float hlast[4] = {0.f, 0.f, 0.f, 0.f};

  // prefetch Gx for t=0
  float gxv[4];
  {
    const GT* gp = Gx + (size_t)(m * 16 + q * 4) * 4096 + gxcol;
#pragma unroll
    for (int r = 0; r < 4; ++r) gxv[r] = gxload(gp + (size_t)r * 4096);
  }

#define BFRAG(kk) (wl[((kk) * 4 + q) * 64 + wcol])

  for (int t = 0; t < T_; ++t) {
    const u16* hs = hbuf + (size_t)(t & 1) * (B_ * H_) + (size_t)arow * 1024 + q * 8;
    f32x4 acc0 = {0.f, 0.f, 0.f, 0.f}, acc1 = {0.f, 0.f, 0.f, 0.f};
    s16x8 ha[8], hb[8];
#pragma unroll
    for (int i = 0; i < 8; ++i) ha[i] = *(const s16x8*)(hs + i * 32);
#pragma unroll
    for (int i = 0; i < 8; ++i) hb[i] = *(const s16x8*)(hs + (8 + i) * 32);
#pragma unroll
    for (int i = 0; i < 8; ++i) {
      f32x4& a = (i & 1) ? acc1 : acc0;
      a = __builtin_amdgcn_mfma_f32_16x16x32_bf16(ha[i], BFRAG(i), a, 0, 0, 0);
    }
#pragma unroll
    for (int i = 0; i < 8; ++i) ha[i] = *(const s16x8*)(hs + (16 + i) * 32);
#pragma unroll
    for (int i = 0; i < 8; ++i) {
      f32x4& a = (i & 1) ? acc1 : acc0;
      a = __builtin_amdgcn_mfma_f32_16x16x32_bf16(hb[i], BFRAG(8 + i), a, 0, 0, 0);
    }
#pragma unroll
    for (int i = 0; i < 8; ++i) hb[i] = *(const s16x8*)(hs + (24 + i) * 32);
#pragma unroll
    for (int i = 0; i < 8; ++i) {
      f32x4& a = (i & 1) ? acc1 : acc0;
      a = __builtin_amdgcn_mfma_f32_16x16x32_bf16(ha[i], BFRAG(16 + i), a, 0, 0, 0);
    }
#pragma unroll
    for (int i = 0; i < 8; ++i) {
      f32x4& a = (i & 1) ? acc1 : acc0;
      a = __builtin_amdgcn_mfma_f32_16x16x32_bf16(hb[i], BFRAG(24 + i), a, 0, 0, 0);
    }

    // prefetch Gx for t+1 (independent of barrier; completes during the spin)
    float gxn[4];
    {
      const int tn = (t + 1) & 511;
      const GT* gp = Gx + (size_t)(tn * 64 + m * 16 + q * 4) * 4096 + gxcol;
#pragma unroll
      for (int r = 0; r < 4; ++r) gxn[r] = gxload(gp + (size_t)r * 4096);
    }

    float v0[4];
#pragma unroll
    for (int r = 0; r < 4; ++r) {
      float x = acc0[r] + acc1[r] + gxv[r];
      v0[r] = (gate == 2) ? tanh_(x) : sigm(x);
    }
#pragma unroll
    for (int r = 0; r < 4; ++r) {
      float a0 = v0[r];
      float a1 = __shfl_xor(a0, 1);
      float a2 = __shfl_xor(a0, 2);
      float a3 = __shfl_xor(a1, 2);
      float fv = (gate == 0) ? a0 : (gate == 1) ? a1 : (gate == 2) ? a2 : a3;
      float iv = (gate == 0) ? a1 : (gate == 1) ? a0 : (gate == 2) ? a3 : a2;
      float gv = (gate == 0) ? a2 : (gate == 1) ? a3 : (gate == 2) ? a0 : a1;
      float ov = (gate == 0) ? a3 : (gate == 1) ? a2 : (gate == 2) ? a1 : a0;
      float cn = fv * cst[r] + iv * gv;
      cst[r] = cn;
      hlast[r] = ov * tanh_(cn);
    }
    if (gate == 0) {
      u16* hd = hbuf + (size_t)((t + 1) & 1) * (B_ * H_);
#pragma unroll
      for (int r = 0; r < 4; ++r) {
        const int row = m * 16 + q * 4 + r;
        out[(size_t)(t * 64 + row) * 1024 + hcol] = hlast[r];
        hd[row * 1024 + hcol] = f2bf(hlast[r]);
      }
    }
#pragma unroll
    for (int r = 0; r < 4; ++r) gxv[r] = gxn[r];

    // -------- per-group flag-vector barrier (no RMW) --------
    __syncthreads();  // all waves' stores drained to L2 before publish
    if (tid == 0)
      __hip_atomic_store(&gflag[g], (unsigned)(t + 1), __ATOMIC_RELEASE,
                         __HIP_MEMORY_SCOPE_AGENT);
    if (w == 0) {
      // wave 0: lane l polls gflag[l]; one coalesced 256B read per round
      for (;;) {
        unsigned v = __hip_atomic_load(&gflag[l], __ATOMIC_RELAXED,
                                       __HIP_MEMORY_SCOPE_AGENT);
        if (__all(v > (unsigned)t)) break;
        __builtin_amdgcn_s_sleep(1);
      }
      (void)__hip_atomic_load(&gflag[0], __ATOMIC_ACQUIRE,
                              __HIP_MEMORY_SCOPE_AGENT);
    }
    __syncthreads();
  }
#undef BFRAG

  if (gate == 0) {
    float* hT = out + (size_t)T_ * B_ * H_;
    float* cT = hT + B_ * H_;
#pragma unroll
    for (int r = 0; r < 4; ++r) {
      const int row = m * 16 + q * 4 + r;
      hT[row * 1024 + hcol] = hlast[r];
      cT[row * 1024 + hcol] = cst[r];
    }
  }
}

// ---------------------------------------------------------------------------
extern "C" void kernel_launch(void* const* d_in, const int* in_sizes, int n_in,
                              void* d_out, int out_size, void* d_ws, size_t ws_size,
                              hipStream_t stream) {
  (void)in_sizes; (void)n_in; (void)out_size;
  const float* x   = (const float*)d_in[0];
  const float* Wf  = (const float*)d_in[1];
  const float* bf_ = (const float*)d_in[2];
  const float* Wi  = (const float*)d_in[3];
  const float* bi_ = (const float*)d_in[4];
  const float* Wg  = (const float*)d_in[5];
  const float* bg_ = (const float*)d_in[6];
  const float* Wo  = (const float*)d_in[7];
  const float* bo_ = (const float*)d_in[8];
  float* out = (float*)d_out;

  uint8_t* ws = (uint8_t*)d_ws;
  const size_t n_gx    = (size_t)MX_ * NG_;
  const size_t sz_xb   = (size_t)MX_ * 1024 * 2;   // 64 MB
  const size_t sz_wxt  = (size_t)4096 * 1024 * 2;  // 8 MB
  const size_t sz_whr  = (size_t)4096 * 1024 * 2;  // 8 MB
  const size_t sz_bias = 4096 * 4;
  const size_t sz_hbuf = (size_t)2 * 64 * 1024 * 2;
  const size_t sz_ctrl = 4096;                     // barrier flags [4][64] + pad
  const size_t fixed = sz_xb + sz_wxt + sz_whr + sz_bias + sz_hbuf + sz_ctrl + 1024;
  const bool f32gx = ws_size >= fixed + n_gx * 4;  // fp32 Gx (512 MB) if it fits
  const size_t sz_gx = n_gx * (f32gx ? 4 : 2);

  size_t off = 0;
  uint8_t* p_gx   = ws;                  off += sz_gx;
  u16*     xb     = (u16*)(ws + off);    off += sz_xb;
  u16*     wxt    = (u16*)(ws + off);    off += sz_wxt;
  u16*     whr    = (u16*)(ws + off);    off += sz_whr;
  float*   biasf  = (float*)(ws + off);  off += sz_bias;
  u16*     hbuf   = (u16*)(ws + off);    off += sz_hbuf;
  unsigned* flags = (unsigned*)(ws + off);

  // zero h0 (both h buffers) + barrier flags (contiguous)
  hipMemsetAsync(hbuf, 0, sz_hbuf + sz_ctrl, stream);
  k_cast_x<<<(MX_ * 1024) / (256 * 8), 256, 0, stream>>>(x, xb);
  k_prep_w<<<4096, 256, 0, stream>>>(Wf, Wi, Wg, Wo, bf_, bi_, bg_, bo_, wxt, whr, biasf);
  if (f32gx) {
    k_gemm_gx<float><<<dim3(256, 32), 256, 0, stream>>>(xb, wxt, biasf, (float*)p_gx);
    k_lstm<float><<<256, 256, 0, stream>>>(whr, (const float*)p_gx, hbuf, out, flags);
  } else {
    k_gemm_gx<u16><<<dim3(256, 32), 256, 0, stream>>>(xb, wxt, biasf, (u16*)p_gx);
    k_lstm<u16><<<256, 256, 0, stream>>>(whr, (const u16*)p_gx, hbuf, out, flags);
  }
}